// Round 8
// baseline (481.714 us; speedup 1.0000x reference)
//
#include <hip/hip_runtime.h>
#include <hip/hip_bf16.h>
#include <cstdint>
#include <cstddef>

#define NPATCH 50000
#define GC 256

typedef __bf16 bf16x8 __attribute__((ext_vector_type(8)));
typedef float  f32x4  __attribute__((ext_vector_type(4)));
typedef float  f32x8  __attribute__((ext_vector_type(8)));

// ---------------- workspace layout (bytes) ----------------
static constexpr size_t XB_OFF    = 0;                         // bf16 x [50048][512]
static constexpr size_t XB_BYTES  = (size_t)50048 * 512 * 2;
static constexpr size_t W1B_OFF   = XB_OFF + XB_BYTES;         // bf16 W1 [512][1024]
static constexpr size_t W1B_BYTES = (size_t)512 * 1024 * 2;
static constexpr size_t W2AB_OFF  = W1B_OFF + W1B_BYTES;       // bf16 W2a [256][512]
static constexpr size_t W2X_BYTES = (size_t)256 * 512 * 2;
static constexpr size_t W2BB_OFF  = W2AB_OFF + W2X_BYTES;      // bf16 W2b [256][512]
static constexpr size_t MUG_OFF   = W2BB_OFF + W2X_BYTES;      // f32 [65536]
static constexpr size_t LVG_OFF   = MUG_OFF + (size_t)65536 * 4;
static constexpr size_t AG_OFF    = LVG_OFF + (size_t)65536 * 4;
static constexpr size_t MPART_OFF = AG_OFF + (size_t)65536 * 4; // f32 [512]
static constexpr size_t SUMA_OFF  = MPART_OFF + (size_t)512 * 4;
static constexpr size_t ZERO_BYTES = SUMA_OFF + 4 - MUG_OFF;   // zero mug..sumA

__device__ __forceinline__ unsigned short f2bf(float f) {
  union { float f; uint32_t u; } v; v.f = f;
  uint32_t u = v.u;
  uint32_t r = (u + 0x7FFFu + ((u >> 16) & 1u)) >> 16;
  return (unsigned short)r;
}
__device__ __forceinline__ float bf2f(uint32_t bits16) {
  union { uint32_t u; float f; } v; v.u = bits16 << 16; return v.f;
}
__device__ __forceinline__ unsigned short cvt_bf16(float f) {
  __bf16 b = (__bf16)f;
  return __builtin_bit_cast(unsigned short, b);
}
__device__ __forceinline__ bf16x8 cvt8(const float4& f0, const float4& f1) {
  f32x8 fv;
  fv[0]=f0.x; fv[1]=f0.y; fv[2]=f0.z; fv[3]=f0.w;
  fv[4]=f1.x; fv[5]=f1.y; fv[6]=f1.z; fv[7]=f1.w;
  return __builtin_convertvector(fv, bf16x8);
}

// ---------------- K0: convert weights f32 -> bf16 ----------------
__global__ void convert_weights(const float* __restrict__ W1,
                                const float* __restrict__ W2a,
                                const float* __restrict__ W2b,
                                unsigned short* __restrict__ W1b,
                                unsigned short* __restrict__ W2ab,
                                unsigned short* __restrict__ W2bb) {
  int i = blockIdx.x * 256 + threadIdx.x;
  if (i < 512 * 1024) W1b[i] = f2bf(W1[i]);
  if (i < 256 * 512) { W2ab[i] = f2bf(W2a[i]); W2bb[i] = f2bf(W2b[i]); }
}

// ---------------- K1: x = relu(h @ W1^T + b1) -> bf16 ----------------
// NO LDS, NO BARRIERS. Each wave owns a 32x64 output tile (acc[2][4]);
// MFMA fragments are loaded DIRECTLY from global into registers with a
// 1-iteration register prefetch:
//   A frag (16x16x32 layout): lane l -> h[row = base + l&15][k = kt*32 +
//     (l>>4)*8 .. +7]  = 32B contiguous per lane (2x float4), cvt -> bf16.
//   B frag: lane l -> W1b[col = base + l&15][same k] = 16B per lane.
// All kt offsets fold into 13-bit load immediates (A: kt*128B <= 3984;
// B: kt*64B) -> near-zero address VALU. B (1MB) is L2-resident; A rows are
// reused x2 within the block via L1 and x4 across the row-tile's col-blocks
// via the XCD remap. Latency hiding = pure wave TLP (no lockstep).
// Block 64x128 (4 waves 2x2), grid 3128 = 8 * 391, bijective XCD remap.
__global__ __launch_bounds__(256) void gemm1(
    const float* __restrict__ h, const unsigned short* __restrict__ W1b,
    const float* __restrict__ b1, unsigned short* __restrict__ xb) {
  const int t  = threadIdx.x;
  const int l  = t & 63;
  const int w  = t >> 6;          // 0..3
  const int wr = w >> 1;          // 0..1 (row half: 32 rows)
  const int wc = w & 1;           // 0..1 (col half: 64 cols)
  const int g  = l >> 4;          // 0..3 (k-chunk)
  const int lr = l & 15;

  // bijective XCD remap: x = XCD, j = per-XCD slot; v = x*391+j linearizes
  // (rowtile, coltile) = (v>>2, v&3) so the 4 col-tiles of a row-tile are
  // adjacent in time on the SAME XCD.
  const int i  = blockIdx.x;
  const int x  = i & 7;
  const int j  = i >> 3;          // 0..390
  const int v  = x * 391 + j;
  const int rt = v >> 2;          // 0..781
  const int ct = v & 3;           // 0..3
  const int rowBase = rt * 64;
  const int colBase = ct * 128;

  // per-lane fragment base pointers
  const float* ap[2];
#pragma unroll
  for (int mm = 0; mm < 2; ++mm) {
    int r = rowBase + wr * 32 + mm * 16 + lr;
    if (r >= NPATCH) r = NPATCH - 1;          // clamp (stores masked later)
    ap[mm] = h + (size_t)r * 1024 + g * 8;
  }
  const unsigned short* bp[4];
#pragma unroll
  for (int nn = 0; nn < 4; ++nn) {
    int c = colBase + wc * 64 + nn * 16 + lr;
    bp[nn] = W1b + (size_t)c * 1024 + g * 8;
  }

  f32x4 acc[2][4];
#pragma unroll
  for (int mm = 0; mm < 2; ++mm)
#pragma unroll
    for (int nn = 0; nn < 4; ++nn) acc[mm][nn] = (f32x4){0.f, 0.f, 0.f, 0.f};

  // prefetch kt=0
  float4 a0[2][2]; bf16x8 bq0[4];
#pragma unroll
  for (int mm = 0; mm < 2; ++mm) {
    a0[mm][0] = *(const float4*)(ap[mm]);
    a0[mm][1] = *(const float4*)(ap[mm] + 4);
  }
#pragma unroll
  for (int nn = 0; nn < 4; ++nn) bq0[nn] = *(const bf16x8*)(bp[nn]);

#pragma unroll 2
  for (int kt = 0; kt < 32; ++kt) {
    // issue kt+1 loads (clamped at the tail -> uniform shape)
    const int kn = (kt + 1 <= 31) ? (kt + 1) : 31;
    float4 a1[2][2]; bf16x8 bq1[4];
#pragma unroll
    for (int mm = 0; mm < 2; ++mm) {
      a1[mm][0] = *(const float4*)(ap[mm] + kn * 32);
      a1[mm][1] = *(const float4*)(ap[mm] + kn * 32 + 4);
    }
#pragma unroll
    for (int nn = 0; nn < 4; ++nn) bq1[nn] = *(const bf16x8*)(bp[nn] + kn * 32);
    // compute kt from the regs prefetched last iteration
    bf16x8 afr[2];
#pragma unroll
    for (int mm = 0; mm < 2; ++mm) afr[mm] = cvt8(a0[mm][0], a0[mm][1]);
#pragma unroll
    for (int mm = 0; mm < 2; ++mm)
#pragma unroll
      for (int nn = 0; nn < 4; ++nn)
        acc[mm][nn] = __builtin_amdgcn_mfma_f32_16x16x32_bf16(afr[mm], bq0[nn], acc[mm][nn], 0, 0, 0);
    // rotate prefetch buffers
#pragma unroll
    for (int mm = 0; mm < 2; ++mm) { a0[mm][0] = a1[mm][0]; a0[mm][1] = a1[mm][1]; }
#pragma unroll
    for (int nn = 0; nn < 4; ++nn) bq0[nn] = bq1[nn];
  }

  // epilogue: relu + bias, store bf16
  float b1v[4];
#pragma unroll
  for (int nn = 0; nn < 4; ++nn) b1v[nn] = b1[colBase + wc * 64 + nn * 16 + lr];
#pragma unroll
  for (int mm = 0; mm < 2; ++mm) {
    const int rb0 = rowBase + wr * 32 + mm * 16 + g * 4;
#pragma unroll
    for (int r = 0; r < 4; ++r) {
      const int row = rb0 + r;
      if (row < NPATCH) {
        unsigned short* xrow = xb + (size_t)row * 512 + colBase + wc * 64;
#pragma unroll
        for (int nn = 0; nn < 4; ++nn) {
          float vv = acc[mm][nn][r] + b1v[nn];
          vv = vv > 0.f ? vv : 0.f;
          xrow[nn * 16 + lr] = cvt_bf16(vv);
        }
      }
    }
  }
}

// ---------------- K2: fa=sig(x@W2a^T+b2a), fb=tanh(x@W2b^T+b2b),
//                      params=(fa*fb)@W3^T+b3, scatter mu/logvar ----------------
// 64 rows/block, full 256 cols; 4 waves, each 64 rows x 64 cols, dual acc.
__global__ __launch_bounds__(256, 2) void gemm2(
    const unsigned short* __restrict__ xb,
    const unsigned short* __restrict__ W2ab, const unsigned short* __restrict__ W2bb,
    const float* __restrict__ b2a, const float* __restrict__ b2b,
    const float* __restrict__ W3, const float* __restrict__ b3,
    const int* __restrict__ coords,
    float* __restrict__ mug, float* __restrict__ lvg) {
  __shared__ __align__(16) unsigned short xs[64 * 40];
  __shared__ __align__(16) unsigned short was[256 * 40];
  __shared__ __align__(16) unsigned short wbs[256 * 40];
  __shared__ float pmu_s[4][64];
  __shared__ float plv_s[4][64];

  const int t = threadIdx.x;
  const int l = t & 63;
  const int w = t >> 6;
  const int g = l >> 4, lr = l & 15;
  const int rowBase = blockIdx.x * 64;

  f32x4 aa[4][4], ab[4][4];
#pragma unroll
  for (int m = 0; m < 4; ++m)
#pragma unroll
    for (int n = 0; n < 4; ++n) {
      aa[m][n] = (f32x4){0.f, 0.f, 0.f, 0.f};
      ab[m][n] = (f32x4){0.f, 0.f, 0.f, 0.f};
    }

  const int xrow = t >> 2;           // 0..63
  const int xc0  = (t & 3) * 8;      // 0,8,16,24
  const int grow = rowBase + xrow;
  const bool xval = grow < NPATCH;

  for (int kt = 0; kt < 16; ++kt) {
    const int k0 = kt * 32;
    __syncthreads();
    if (xval) {
      *(int4*)&xs[xrow * 40 + xc0] = *(const int4*)(xb + (size_t)grow * 512 + k0 + xc0);
    } else {
      int4 z = {0, 0, 0, 0};
      *(int4*)&xs[xrow * 40 + xc0] = z;
    }
#pragma unroll
    for (int j = 0; j < 4; ++j) {
      int rrow = (t >> 2) + 64 * j;  // 0..255
      *(int4*)&was[rrow * 40 + xc0] = *(const int4*)(W2ab + (size_t)rrow * 512 + k0 + xc0);
      *(int4*)&wbs[rrow * 40 + xc0] = *(const int4*)(W2bb + (size_t)rrow * 512 + k0 + xc0);
    }
    __syncthreads();

    bf16x8 af[4], ba[4], bb[4];
#pragma unroll
    for (int m = 0; m < 4; ++m)
      af[m] = *(const bf16x8*)&xs[(m * 16 + lr) * 40 + g * 8];
#pragma unroll
    for (int n = 0; n < 4; ++n) {
      int brow = w * 64 + n * 16 + lr;
      ba[n] = *(const bf16x8*)&was[brow * 40 + g * 8];
      bb[n] = *(const bf16x8*)&wbs[brow * 40 + g * 8];
    }
#pragma unroll
    for (int m = 0; m < 4; ++m)
#pragma unroll
      for (int n = 0; n < 4; ++n) {
        aa[m][n] = __builtin_amdgcn_mfma_f32_16x16x32_bf16(af[m], ba[n], aa[m][n], 0, 0, 0);
        ab[m][n] = __builtin_amdgcn_mfma_f32_16x16x32_bf16(af[m], bb[n], ab[m][n], 0, 0, 0);
      }
  }

  // epilogue: per output row, mu/lv = sum_col (sig*tanh)*W3[.,col]
  float b2av[4], b2bv[4], w30v[4], w31v[4];
#pragma unroll
  for (int n = 0; n < 4; ++n) {
    int col = w * 64 + n * 16 + lr;
    b2av[n] = b2a[col]; b2bv[n] = b2b[col];
    w30v[n] = W3[col];  w31v[n] = W3[256 + col];
  }
#pragma unroll
  for (int m = 0; m < 4; ++m) {
#pragma unroll
    for (int r = 0; r < 4; ++r) {
      float pm = 0.f, pl = 0.f;
#pragma unroll
      for (int n = 0; n < 4; ++n) {
        float a = 1.f / (1.f + __expf(-(aa[m][n][r] + b2av[n])));
        float b = tanhf(ab[m][n][r] + b2bv[n]);
        float p = a * b;
        pm += p * w30v[n];
        pl += p * w31v[n];
      }
#pragma unroll
      for (int d = 1; d < 16; d <<= 1) {
        pm += __shfl_xor(pm, d, 64);
        pl += __shfl_xor(pl, d, 64);
      }
      if (lr == 0) {
        pmu_s[w][m * 16 + g * 4 + r] = pm;
        plv_s[w][m * 16 + g * 4 + r] = pl;
      }
    }
  }
  __syncthreads();
  if (t < 64) {
    float mu = pmu_s[0][t] + pmu_s[1][t] + pmu_s[2][t] + pmu_s[3][t] + b3[0];
    float lv = plv_s[0][t] + plv_s[1][t] + plv_s[2][t] + plv_s[3][t] + b3[1];
    int row = rowBase + t;
    if (row < NPATCH) {
      int gx = coords[2 * row] >> 8;       // /256
      int gy = coords[2 * row + 1] >> 8;
      int cell = gy * GC + gx;
      mug[cell] = mu;
      lvg[cell] = lv;
    }
  }
}

// ---------------- K3: kl_div, 3x3 conv, reparam, sigmoid -> A grid ----------------
__global__ void grid_ops(const float* __restrict__ mug, const float* __restrict__ lvg,
                         const float* __restrict__ eps, const float* __restrict__ kern,
                         const int* __restrict__ slide, float* __restrict__ Ag,
                         float* __restrict__ out_kl) {
  int cell = blockIdx.x * 256 + threadIdx.x;
  int iy = cell >> 8, ix = cell & 255;
  float mu = mug[cell], lv = lvg[cell];
  int sl = slide[0];
  float pm  = (sl == 0) ? -5.0f : 0.0f;
  float plv = (sl == 0) ? -1.0f : 3.0f;
  float d = pm - mu;
  out_kl[cell] = (plv - lv) * 0.5f + (lv * lv + d * d) / (2.0f * plv * plv) - 0.5f;
  float s = 0.f;
#pragma unroll
  for (int dy = 0; dy < 3; ++dy) {
#pragma unroll
    for (int dx = 0; dx < 3; ++dx) {
      int y = iy + dy - 1, x = ix + dx - 1;
      if (y >= 0 && y < GC && x >= 0 && x < GC)
        s += mug[y * GC + x] * kern[dy * 3 + dx];
    }
  }
  float sample = s + eps[cell] * __expf(0.5f * lv);
  Ag[cell] = 1.f / (1.f + __expf(-sample));
}

// ---------------- K4: gather patch_A, accumulate sumA and patch_A @ x ----------------
__global__ __launch_bounds__(256) void patch_pass(
    const float* __restrict__ Ag, const int* __restrict__ coords,
    const unsigned short* __restrict__ xb, float* __restrict__ out_pA,
    float* __restrict__ Mpart, float* __restrict__ sumA) {
  __shared__ float als[256];
  __shared__ float swave[4];
  const int t = threadIdx.x;
  const int base = blockIdx.x * 256;
  const int row = base + t;
  float a = 0.f;
  if (row < NPATCH) {
    int gx = coords[2 * row] >> 8;
    int gy = coords[2 * row + 1] >> 8;
    a = Ag[gy * GC + gx];
    out_pA[row] = a;
  }
  als[t] = a;
  float sa = a;
#pragma unroll
  for (int d = 1; d < 64; d <<= 1) sa += __shfl_xor(sa, d, 64);
  if ((t & 63) == 0) swave[t >> 6] = sa;
  __syncthreads();
  if (t == 0) atomicAdd(sumA, swave[0] + swave[1] + swave[2] + swave[3]);

  const int nrows = min(256, NPATCH - base);
  float m0 = 0.f, m1 = 0.f;
  for (int r = 0; r < nrows; ++r) {
    float av = als[r];
    const uint32_t* p = (const uint32_t*)(xb + (size_t)(base + r) * 512);
    uint32_t v = p[t];
    m0 += av * bf2f(v & 0xFFFFu);
    m1 += av * bf2f(v >> 16);
  }
  atomicAdd(&Mpart[t * 2 + 0], m0);
  atomicAdd(&Mpart[t * 2 + 1], m1);
}

// ---------------- K5: logits, softmax, argmax, small outputs ----------------
__global__ void finalize(const float* __restrict__ Mpart, const float* __restrict__ sumA,
                         const float* __restrict__ Wc, const float* __restrict__ bc,
                         float* __restrict__ out) {
  const int t = threadIdx.x;  // 64 threads
  float s = sumA[0];
  float l0 = 0.f, l1 = 0.f;
#pragma unroll
  for (int j = 0; j < 8; ++j) {
    int c = t * 8 + j;
    float m = Mpart[c] / s;
    l0 += m * Wc[c];
    l1 += m * Wc[512 + c];
  }
#pragma unroll
  for (int d = 1; d < 64; d <<= 1) {
    l0 += __shfl_xor(l0, d, 64);
    l1 += __shfl_xor(l1, d, 64);
  }
  if (t == 0) {
    l0 += bc[0]; l1 += bc[1];
    float mx = fmaxf(l0, l1);
    float e0 = __expf(l0 - mx), e1 = __expf(l1 - mx);
    float inv = 1.f / (e0 + e1);
    float p0 = e0 * inv, p1 = e1 * inv;
    out[0] = l0; out[1] = l1;            // top_instance
    out[2] = p0; out[3] = p1;            // Y_prob
    out[4] = (l1 > l0) ? 1.0f : 0.0f;    // Y_hat
    out[65541] = p0; out[65542] = p1;    // y_probs
  }
}

extern "C" void kernel_launch(void* const* d_in, const int* in_sizes, int n_in,
                              void* d_out, int out_size, void* d_ws, size_t ws_size,
                              hipStream_t stream) {
  const float* h      = (const float*)d_in[0];
  const int*   coords = (const int*)d_in[1];
  const float* eps    = (const float*)d_in[2];
  const float* W1     = (const float*)d_in[3];
  const float* b1     = (const float*)d_in[4];
  const float* W2a    = (const float*)d_in[5];
  const float* b2a    = (const float*)d_in[6];
  const float* W2b    = (const float*)d_in[7];
  const float* b2b    = (const float*)d_in[8];
  const float* W3     = (const float*)d_in[9];
  const float* b3     = (const float*)d_in[10];
  const float* Wc     = (const float*)d_in[11];
  const float* bc     = (const float*)d_in[12];
  const float* kern   = (const float*)d_in[13];
  const int*   slide  = (const int*)d_in[16];
  float* out = (float*)d_out;
  char*  ws  = (char*)d_ws;

  unsigned short* xb   = (unsigned short*)(ws + XB_OFF);
  unsigned short* W1b  = (unsigned short*)(ws + W1B_OFF);
  unsigned short* W2ab = (unsigned short*)(ws + W2AB_OFF);
  unsigned short* W2bb = (unsigned short*)(ws + W2BB_OFF);
  float* mug   = (float*)(ws + MUG_OFF);
  float* lvg   = (float*)(ws + LVG_OFF);
  float* Ag    = (float*)(ws + AG_OFF);
  float* Mpart = (float*)(ws + MPART_OFF);
  float* sumA  = (float*)(ws + SUMA_OFF);

  hipMemsetAsync(ws + MUG_OFF, 0, ZERO_BYTES, stream);

  convert_weights<<<2048, 256, 0, stream>>>(W1, W2a, W2b, W1b, W2ab, W2bb);
  gemm1<<<3128, 256, 0, stream>>>(h, W1b, b1, xb);
  gemm2<<<782, 256, 0, stream>>>(xb, W2ab, W2bb, b2a, b2b, W3, b3, coords, mug, lvg);
  grid_ops<<<256, 256, 0, stream>>>(mug, lvg, eps, kern, slide, Ag, out + 5);
  patch_pass<<<196, 256, 0, stream>>>(Ag, coords, xb, out + 65543, Mpart, sumA);
  finalize<<<1, 64, 0, stream>>>(Mpart, sumA, Wc, bc, out);
}

// Round 9
// 202.856 us; speedup vs baseline: 2.3747x; 2.3747x over previous
//
#include <hip/hip_runtime.h>
#include <hip/hip_bf16.h>
#include <cstdint>
#include <cstddef>

#define NPATCH 50000
#define GC 256

typedef __bf16 bf16x8 __attribute__((ext_vector_type(8)));
typedef float  f32x4  __attribute__((ext_vector_type(4)));
typedef float  f32x8  __attribute__((ext_vector_type(8)));

// ---------------- workspace layout (bytes) ----------------
static constexpr size_t XB_OFF    = 0;                         // bf16 x [50048][512]
static constexpr size_t XB_BYTES  = (size_t)50048 * 512 * 2;
static constexpr size_t W1B_OFF   = XB_OFF + XB_BYTES;         // bf16 W1 [512][1024]
static constexpr size_t W1B_BYTES = (size_t)512 * 1024 * 2;
static constexpr size_t W2AB_OFF  = W1B_OFF + W1B_BYTES;       // bf16 W2a [256][512]
static constexpr size_t W2X_BYTES = (size_t)256 * 512 * 2;
static constexpr size_t W2BB_OFF  = W2AB_OFF + W2X_BYTES;      // bf16 W2b [256][512]
static constexpr size_t MUG_OFF   = W2BB_OFF + W2X_BYTES;      // f32 [65536]
static constexpr size_t LVG_OFF   = MUG_OFF + (size_t)65536 * 4;
static constexpr size_t AG_OFF    = LVG_OFF + (size_t)65536 * 4;
static constexpr size_t MPART_OFF = AG_OFF + (size_t)65536 * 4; // f32 [512]
static constexpr size_t SUMA_OFF  = MPART_OFF + (size_t)512 * 4;
static constexpr size_t ZERO_BYTES = SUMA_OFF + 4 - MUG_OFF;   // zero mug..sumA

__device__ __forceinline__ unsigned short f2bf(float f) {
  union { float f; uint32_t u; } v; v.f = f;
  uint32_t u = v.u;
  uint32_t r = (u + 0x7FFFu + ((u >> 16) & 1u)) >> 16;
  return (unsigned short)r;
}
__device__ __forceinline__ float bf2f(uint32_t bits16) {
  union { uint32_t u; float f; } v; v.u = bits16 << 16; return v.f;
}
__device__ __forceinline__ unsigned short cvt_bf16(float f) {
  __bf16 b = (__bf16)f;
  return __builtin_bit_cast(unsigned short, b);
}
__device__ __forceinline__ void gld16(const void* g, void* l) {
  __builtin_amdgcn_global_load_lds(
      (const __attribute__((address_space(1))) void*)g,
      (__attribute__((address_space(3))) void*)l, 16, 0, 0);
}
__device__ __forceinline__ bf16x8 cvt8(const float4& f0, const float4& f1) {
  f32x8 fv;
  fv[0]=f0.x; fv[1]=f0.y; fv[2]=f0.z; fv[3]=f0.w;
  fv[4]=f1.x; fv[5]=f1.y; fv[6]=f1.z; fv[7]=f1.w;
  return __builtin_convertvector(fv, bf16x8);
}

// ---------------- K0: convert weights f32 -> bf16 ----------------
__global__ void convert_weights(const float* __restrict__ W1,
                                const float* __restrict__ W2a,
                                const float* __restrict__ W2b,
                                unsigned short* __restrict__ W1b,
                                unsigned short* __restrict__ W2ab,
                                unsigned short* __restrict__ W2bb) {
  int i = blockIdx.x * 256 + threadIdx.x;
  if (i < 512 * 1024) W1b[i] = f2bf(W1[i]);
  if (i < 256 * 512) { W2ab[i] = f2bf(W2a[i]); W2bb[i] = f2bf(W2b[i]); }
}

// ---------------- K1: x = relu(h @ W1^T + b1) -> bf16 ----------------
// R6 sync structure (single __syncthreads/iter, dbuf LDS, gld16-B, reg-staged
// A) with a HIGHER-REUSE tile: block 128x256, 4 waves (2x2) of 64x128 each,
// acc[4][8] (128 AGPR). Per iter a thread does 12 frag-reads -> 32 MFMAs
// (2.67 MFMA/read vs R6's 2.0) and 2x the compute against the same per-iter
// barrier drain. __launch_bounds__(256,2) targets 2 blocks/CU (<=256 regs).
__global__ __launch_bounds__(256, 2) void gemm1(
    const float* __restrict__ h, const unsigned short* __restrict__ W1b,
    const float* __restrict__ b1, unsigned short* __restrict__ xb) {
  __shared__ __align__(16) unsigned short As[2][128 * 32];  // 2 x 8 KB
  __shared__ __align__(16) unsigned short Bs[2][256 * 32];  // 2 x 16 KB

  const int t  = threadIdx.x;
  const int l  = t & 63;
  const int w  = t >> 6;          // 0..3
  const int wr = w >> 1;          // 0..1 (row half: 64 rows)
  const int wc = w & 1;           // 0..1 (col half: 128 cols)
  const int g  = l >> 4;          // 0..3
  const int lr = l & 15;

  const int rt = blockIdx.x >> 1;   // 0..390
  const int ct = blockIdx.x & 1;    // 0..1
  const int rowBase = rt * 128;
  const int colBase = ct * 256;

  // ---- A staging: thread t covers rows t>>2 and 64+(t>>2), 32B chunk t&3 ----
  const int ar = t >> 2;
  const int aj = t & 3;
  int gr0 = rowBase + ar;       if (gr0 >= NPATCH) gr0 = NPATCH - 1;
  int gr1 = rowBase + 64 + ar;  if (gr1 >= NPATCH) gr1 = NPATCH - 1;
  const float* asrc0 = h + (size_t)gr0 * 1024 + aj * 8;
  const float* asrc1 = h + (size_t)gr1 * 1024 + aj * 8;
  const int adst0 = t * 8;           // ushort idx in As ([row][32] layout)
  const int adst1 = 2048 + t * 8;

  // ---- B staging: 4 rounds; round r covers col colBase+r*64+(t>>2), chunk t&3
  const unsigned short* bsrc[4];
#pragma unroll
  for (int r = 0; r < 4; ++r)
    bsrc[r] = W1b + (size_t)(colBase + r * 64 + (t >> 2)) * 1024 + (t & 3) * 8;
  // dst ushort idx = r*2048 + t*8  ([col][32] layout)

  f32x4 acc[4][8];
#pragma unroll
  for (int mm = 0; mm < 4; ++mm)
#pragma unroll
    for (int nn = 0; nn < 8; ++nn) acc[mm][nn] = (f32x4){0.f, 0.f, 0.f, 0.f};

  // ---- prologue: stage tile 0, preload A(1) regs ----
  float4 s00, s01, s10, s11;
  {
#pragma unroll
    for (int r = 0; r < 4; ++r) gld16(bsrc[r], &Bs[0][r * 2048 + t * 8]);
    float4 t00 = *(const float4*)(asrc0 + 0);
    float4 t01 = *(const float4*)(asrc0 + 4);
    float4 t10 = *(const float4*)(asrc1 + 0);
    float4 t11 = *(const float4*)(asrc1 + 4);
    *(bf16x8*)&As[0][adst0] = cvt8(t00, t01);
    *(bf16x8*)&As[0][adst1] = cvt8(t10, t11);
    s00 = *(const float4*)(asrc0 + 32);
    s01 = *(const float4*)(asrc0 + 36);
    s10 = *(const float4*)(asrc1 + 32);
    s11 = *(const float4*)(asrc1 + 36);
  }
  __syncthreads();

  int cur = 0;
  for (int kt = 0; kt < 32; ++kt) {
    // stage tile kt+1 into buf[cur^1] (free since the barrier ending kt-1)
    if (kt < 31) {
#pragma unroll
      for (int r = 0; r < 4; ++r)
        gld16(bsrc[r] + (kt + 1) * 32, &Bs[cur ^ 1][r * 2048 + t * 8]);
      *(bf16x8*)&As[cur ^ 1][adst0] = cvt8(s00, s01);
      *(bf16x8*)&As[cur ^ 1][adst1] = cvt8(s10, s11);
      if (kt < 30) {
        s00 = *(const float4*)(asrc0 + (kt + 2) * 32);
        s01 = *(const float4*)(asrc0 + (kt + 2) * 32 + 4);
        s10 = *(const float4*)(asrc1 + (kt + 2) * 32);
        s11 = *(const float4*)(asrc1 + (kt + 2) * 32 + 4);
      }
    }
    // compute tile kt from buf[cur]
    bf16x8 af[4], bfr[8];
#pragma unroll
    for (int mm = 0; mm < 4; ++mm)
      af[mm] = *(const bf16x8*)&As[cur][(wr * 64 + mm * 16 + lr) * 32 + g * 8];
#pragma unroll
    for (int nn = 0; nn < 8; ++nn)
      bfr[nn] = *(const bf16x8*)&Bs[cur][(wc * 128 + nn * 16 + lr) * 32 + g * 8];
#pragma unroll
    for (int mm = 0; mm < 4; ++mm)
#pragma unroll
      for (int nn = 0; nn < 8; ++nn)
        acc[mm][nn] = __builtin_amdgcn_mfma_f32_16x16x32_bf16(af[mm], bfr[nn], acc[mm][nn], 0, 0, 0);
    __syncthreads();
    cur ^= 1;
  }

  // epilogue: relu + bias, store bf16
  float b1v[8];
#pragma unroll
  for (int nn = 0; nn < 8; ++nn) b1v[nn] = b1[colBase + wc * 128 + nn * 16 + lr];
#pragma unroll
  for (int mm = 0; mm < 4; ++mm) {
    const int rb0 = rowBase + wr * 64 + mm * 16 + g * 4;
#pragma unroll
    for (int r = 0; r < 4; ++r) {
      const int row = rb0 + r;
      if (row < NPATCH) {
        unsigned short* xrow = xb + (size_t)row * 512 + colBase + wc * 128;
#pragma unroll
        for (int nn = 0; nn < 8; ++nn) {
          float vv = acc[mm][nn][r] + b1v[nn];
          vv = vv > 0.f ? vv : 0.f;
          xrow[nn * 16 + lr] = cvt_bf16(vv);
        }
      }
    }
  }
}

// ---------------- K2: fa=sig(x@W2a^T+b2a), fb=tanh(x@W2b^T+b2b),
//                      params=(fa*fb)@W3^T+b3, scatter mu/logvar ----------------
// 64 rows/block, full 256 cols; 4 waves, each 64 rows x 64 cols, dual acc.
__global__ __launch_bounds__(256, 2) void gemm2(
    const unsigned short* __restrict__ xb,
    const unsigned short* __restrict__ W2ab, const unsigned short* __restrict__ W2bb,
    const float* __restrict__ b2a, const float* __restrict__ b2b,
    const float* __restrict__ W3, const float* __restrict__ b3,
    const int* __restrict__ coords,
    float* __restrict__ mug, float* __restrict__ lvg) {
  __shared__ __align__(16) unsigned short xs[64 * 40];
  __shared__ __align__(16) unsigned short was[256 * 40];
  __shared__ __align__(16) unsigned short wbs[256 * 40];
  __shared__ float pmu_s[4][64];
  __shared__ float plv_s[4][64];

  const int t = threadIdx.x;
  const int l = t & 63;
  const int w = t >> 6;
  const int g = l >> 4, lr = l & 15;
  const int rowBase = blockIdx.x * 64;

  f32x4 aa[4][4], ab[4][4];
#pragma unroll
  for (int m = 0; m < 4; ++m)
#pragma unroll
    for (int n = 0; n < 4; ++n) {
      aa[m][n] = (f32x4){0.f, 0.f, 0.f, 0.f};
      ab[m][n] = (f32x4){0.f, 0.f, 0.f, 0.f};
    }

  const int xrow = t >> 2;           // 0..63
  const int xc0  = (t & 3) * 8;      // 0,8,16,24
  const int grow = rowBase + xrow;
  const bool xval = grow < NPATCH;

  for (int kt = 0; kt < 16; ++kt) {
    const int k0 = kt * 32;
    __syncthreads();
    if (xval) {
      *(int4*)&xs[xrow * 40 + xc0] = *(const int4*)(xb + (size_t)grow * 512 + k0 + xc0);
    } else {
      int4 z = {0, 0, 0, 0};
      *(int4*)&xs[xrow * 40 + xc0] = z;
    }
#pragma unroll
    for (int j = 0; j < 4; ++j) {
      int rrow = (t >> 2) + 64 * j;  // 0..255
      *(int4*)&was[rrow * 40 + xc0] = *(const int4*)(W2ab + (size_t)rrow * 512 + k0 + xc0);
      *(int4*)&wbs[rrow * 40 + xc0] = *(const int4*)(W2bb + (size_t)rrow * 512 + k0 + xc0);
    }
    __syncthreads();

    bf16x8 af[4], ba[4], bb[4];
#pragma unroll
    for (int m = 0; m < 4; ++m)
      af[m] = *(const bf16x8*)&xs[(m * 16 + lr) * 40 + g * 8];
#pragma unroll
    for (int n = 0; n < 4; ++n) {
      int brow = w * 64 + n * 16 + lr;
      ba[n] = *(const bf16x8*)&was[brow * 40 + g * 8];
      bb[n] = *(const bf16x8*)&wbs[brow * 40 + g * 8];
    }
#pragma unroll
    for (int m = 0; m < 4; ++m)
#pragma unroll
      for (int n = 0; n < 4; ++n) {
        aa[m][n] = __builtin_amdgcn_mfma_f32_16x16x32_bf16(af[m], ba[n], aa[m][n], 0, 0, 0);
        ab[m][n] = __builtin_amdgcn_mfma_f32_16x16x32_bf16(af[m], bb[n], ab[m][n], 0, 0, 0);
      }
  }

  // epilogue: per output row, mu/lv = sum_col (sig*tanh)*W3[.,col]
  float b2av[4], b2bv[4], w30v[4], w31v[4];
#pragma unroll
  for (int n = 0; n < 4; ++n) {
    int col = w * 64 + n * 16 + lr;
    b2av[n] = b2a[col]; b2bv[n] = b2b[col];
    w30v[n] = W3[col];  w31v[n] = W3[256 + col];
  }
#pragma unroll
  for (int m = 0; m < 4; ++m) {
#pragma unroll
    for (int r = 0; r < 4; ++r) {
      float pm = 0.f, pl = 0.f;
#pragma unroll
      for (int n = 0; n < 4; ++n) {
        float a = 1.f / (1.f + __expf(-(aa[m][n][r] + b2av[n])));
        float b = tanhf(ab[m][n][r] + b2bv[n]);
        float p = a * b;
        pm += p * w30v[n];
        pl += p * w31v[n];
      }
#pragma unroll
      for (int d = 1; d < 16; d <<= 1) {
        pm += __shfl_xor(pm, d, 64);
        pl += __shfl_xor(pl, d, 64);
      }
      if (lr == 0) {
        pmu_s[w][m * 16 + g * 4 + r] = pm;
        plv_s[w][m * 16 + g * 4 + r] = pl;
      }
    }
  }
  __syncthreads();
  if (t < 64) {
    float mu = pmu_s[0][t] + pmu_s[1][t] + pmu_s[2][t] + pmu_s[3][t] + b3[0];
    float lv = plv_s[0][t] + plv_s[1][t] + plv_s[2][t] + plv_s[3][t] + b3[1];
    int row = rowBase + t;
    if (row < NPATCH) {
      int gx = coords[2 * row] >> 8;       // /256
      int gy = coords[2 * row + 1] >> 8;
      int cell = gy * GC + gx;
      mug[cell] = mu;
      lvg[cell] = lv;
    }
  }
}

// ---------------- K3: kl_div, 3x3 conv, reparam, sigmoid -> A grid ----------------
__global__ void grid_ops(const float* __restrict__ mug, const float* __restrict__ lvg,
                         const float* __restrict__ eps, const float* __restrict__ kern,
                         const int* __restrict__ slide, float* __restrict__ Ag,
                         float* __restrict__ out_kl) {
  int cell = blockIdx.x * 256 + threadIdx.x;
  int iy = cell >> 8, ix = cell & 255;
  float mu = mug[cell], lv = lvg[cell];
  int sl = slide[0];
  float pm  = (sl == 0) ? -5.0f : 0.0f;
  float plv = (sl == 0) ? -1.0f : 3.0f;
  float d = pm - mu;
  out_kl[cell] = (plv - lv) * 0.5f + (lv * lv + d * d) / (2.0f * plv * plv) - 0.5f;
  float s = 0.f;
#pragma unroll
  for (int dy = 0; dy < 3; ++dy) {
#pragma unroll
    for (int dx = 0; dx < 3; ++dx) {
      int y = iy + dy - 1, x = ix + dx - 1;
      if (y >= 0 && y < GC && x >= 0 && x < GC)
        s += mug[y * GC + x] * kern[dy * 3 + dx];
    }
  }
  float sample = s + eps[cell] * __expf(0.5f * lv);
  Ag[cell] = 1.f / (1.f + __expf(-sample));
}

// ---------------- K4: gather patch_A, accumulate sumA and patch_A @ x ----------------
__global__ __launch_bounds__(256) void patch_pass(
    const float* __restrict__ Ag, const int* __restrict__ coords,
    const unsigned short* __restrict__ xb, float* __restrict__ out_pA,
    float* __restrict__ Mpart, float* __restrict__ sumA) {
  __shared__ float als[256];
  __shared__ float swave[4];
  const int t = threadIdx.x;
  const int base = blockIdx.x * 256;
  const int row = base + t;
  float a = 0.f;
  if (row < NPATCH) {
    int gx = coords[2 * row] >> 8;
    int gy = coords[2 * row + 1] >> 8;
    a = Ag[gy * GC + gx];
    out_pA[row] = a;
  }
  als[t] = a;
  float sa = a;
#pragma unroll
  for (int d = 1; d < 64; d <<= 1) sa += __shfl_xor(sa, d, 64);
  if ((t & 63) == 0) swave[t >> 6] = sa;
  __syncthreads();
  if (t == 0) atomicAdd(sumA, swave[0] + swave[1] + swave[2] + swave[3]);

  const int nrows = min(256, NPATCH - base);
  float m0 = 0.f, m1 = 0.f;
  for (int r = 0; r < nrows; ++r) {
    float av = als[r];
    const uint32_t* p = (const uint32_t*)(xb + (size_t)(base + r) * 512);
    uint32_t v = p[t];
    m0 += av * bf2f(v & 0xFFFFu);
    m1 += av * bf2f(v >> 16);
  }
  atomicAdd(&Mpart[t * 2 + 0], m0);
  atomicAdd(&Mpart[t * 2 + 1], m1);
}

// ---------------- K5: logits, softmax, argmax, small outputs ----------------
__global__ void finalize(const float* __restrict__ Mpart, const float* __restrict__ sumA,
                         const float* __restrict__ Wc, const float* __restrict__ bc,
                         float* __restrict__ out) {
  const int t = threadIdx.x;  // 64 threads
  float s = sumA[0];
  float l0 = 0.f, l1 = 0.f;
#pragma unroll
  for (int j = 0; j < 8; ++j) {
    int c = t * 8 + j;
    float m = Mpart[c] / s;
    l0 += m * Wc[c];
    l1 += m * Wc[512 + c];
  }
#pragma unroll
  for (int d = 1; d < 64; d <<= 1) {
    l0 += __shfl_xor(l0, d, 64);
    l1 += __shfl_xor(l1, d, 64);
  }
  if (t == 0) {
    l0 += bc[0]; l1 += bc[1];
    float mx = fmaxf(l0, l1);
    float e0 = __expf(l0 - mx), e1 = __expf(l1 - mx);
    float inv = 1.f / (e0 + e1);
    float p0 = e0 * inv, p1 = e1 * inv;
    out[0] = l0; out[1] = l1;            // top_instance
    out[2] = p0; out[3] = p1;            // Y_prob
    out[4] = (l1 > l0) ? 1.0f : 0.0f;    // Y_hat
    out[65541] = p0; out[65542] = p1;    // y_probs
  }
}

extern "C" void kernel_launch(void* const* d_in, const int* in_sizes, int n_in,
                              void* d_out, int out_size, void* d_ws, size_t ws_size,
                              hipStream_t stream) {
  const float* h      = (const float*)d_in[0];
  const int*   coords = (const int*)d_in[1];
  const float* eps    = (const float*)d_in[2];
  const float* W1     = (const float*)d_in[3];
  const float* b1     = (const float*)d_in[4];
  const float* W2a    = (const float*)d_in[5];
  const float* b2a    = (const float*)d_in[6];
  const float* W2b    = (const float*)d_in[7];
  const float* b2b    = (const float*)d_in[8];
  const float* W3     = (const float*)d_in[9];
  const float* b3     = (const float*)d_in[10];
  const float* Wc     = (const float*)d_in[11];
  const float* bc     = (const float*)d_in[12];
  const float* kern   = (const float*)d_in[13];
  const int*   slide  = (const int*)d_in[16];
  float* out = (float*)d_out;
  char*  ws  = (char*)d_ws;

  unsigned short* xb   = (unsigned short*)(ws + XB_OFF);
  unsigned short* W1b  = (unsigned short*)(ws + W1B_OFF);
  unsigned short* W2ab = (unsigned short*)(ws + W2AB_OFF);
  unsigned short* W2bb = (unsigned short*)(ws + W2BB_OFF);
  float* mug   = (float*)(ws + MUG_OFF);
  float* lvg   = (float*)(ws + LVG_OFF);
  float* Ag    = (float*)(ws + AG_OFF);
  float* Mpart = (float*)(ws + MPART_OFF);
  float* sumA  = (float*)(ws + SUMA_OFF);

  hipMemsetAsync(ws + MUG_OFF, 0, ZERO_BYTES, stream);

  convert_weights<<<2048, 256, 0, stream>>>(W1, W2a, W2b, W1b, W2ab, W2bb);
  gemm1<<<782, 256, 0, stream>>>(h, W1b, b1, xb);
  gemm2<<<782, 256, 0, stream>>>(xb, W2ab, W2bb, b2a, b2b, W3, b3, coords, mug, lvg);
  grid_ops<<<256, 256, 0, stream>>>(mug, lvg, eps, kern, slide, Ag, out + 5);
  patch_pass<<<196, 256, 0, stream>>>(Ag, coords, xb, out + 65543, Mpart, sumA);
  finalize<<<1, 64, 0, stream>>>(Mpart, sumA, Wc, bc, out);
}

// Round 10
// 201.093 us; speedup vs baseline: 2.3955x; 1.0088x over previous
//
#include <hip/hip_runtime.h>
#include <hip/hip_bf16.h>
#include <cstdint>
#include <cstddef>

#define NPATCH 50000
#define GC 256

typedef __bf16 bf16x8 __attribute__((ext_vector_type(8)));
typedef float  f32x4  __attribute__((ext_vector_type(4)));
typedef float  f32x8  __attribute__((ext_vector_type(8)));

// ---------------- workspace layout (bytes) ----------------
static constexpr size_t XB_OFF    = 0;                         // bf16 x [50048][512]
static constexpr size_t XB_BYTES  = (size_t)50048 * 512 * 2;
static constexpr size_t W1B_OFF   = XB_OFF + XB_BYTES;         // bf16 W1 [512][1024]
static constexpr size_t W1B_BYTES = (size_t)512 * 1024 * 2;
static constexpr size_t W2AB_OFF  = W1B_OFF + W1B_BYTES;       // bf16 W2a [256][512]
static constexpr size_t W2X_BYTES = (size_t)256 * 512 * 2;
static constexpr size_t W2BB_OFF  = W2AB_OFF + W2X_BYTES;      // bf16 W2b [256][512]
static constexpr size_t MUG_OFF   = W2BB_OFF + W2X_BYTES;      // f32 [65536]
static constexpr size_t LVG_OFF   = MUG_OFF + (size_t)65536 * 4;
static constexpr size_t AG_OFF    = LVG_OFF + (size_t)65536 * 4;
static constexpr size_t MPART_OFF = AG_OFF + (size_t)65536 * 4; // f32 [512]
static constexpr size_t SUMA_OFF  = MPART_OFF + (size_t)512 * 4;
static constexpr size_t ZERO_BYTES = SUMA_OFF + 4 - MUG_OFF;   // zero mug..sumA

__device__ __forceinline__ unsigned short f2bf(float f) {
  union { float f; uint32_t u; } v; v.f = f;
  uint32_t u = v.u;
  uint32_t r = (u + 0x7FFFu + ((u >> 16) & 1u)) >> 16;
  return (unsigned short)r;
}
__device__ __forceinline__ float bf2f(uint32_t bits16) {
  union { uint32_t u; float f; } v; v.u = bits16 << 16; return v.f;
}
__device__ __forceinline__ unsigned short cvt_bf16(float f) {
  __bf16 b = (__bf16)f;
  return __builtin_bit_cast(unsigned short, b);
}
__device__ __forceinline__ void gld16(const void* g, void* l) {
  __builtin_amdgcn_global_load_lds(
      (const __attribute__((address_space(1))) void*)g,
      (__attribute__((address_space(3))) void*)l, 16, 0, 0);
}
__device__ __forceinline__ bf16x8 cvt8(const float4& f0, const float4& f1) {
  f32x8 fv;
  fv[0]=f0.x; fv[1]=f0.y; fv[2]=f0.z; fv[3]=f0.w;
  fv[4]=f1.x; fv[5]=f1.y; fv[6]=f1.z; fv[7]=f1.w;
  return __builtin_convertvector(fv, bf16x8);
}

// ---------------- K0: convert weights f32 -> bf16 ----------------
__global__ void convert_weights(const float* __restrict__ W1,
                                const float* __restrict__ W2a,
                                const float* __restrict__ W2b,
                                unsigned short* __restrict__ W1b,
                                unsigned short* __restrict__ W2ab,
                                unsigned short* __restrict__ W2bb) {
  int i = blockIdx.x * 256 + threadIdx.x;
  if (i < 512 * 1024) W1b[i] = f2bf(W1[i]);
  if (i < 256 * 512) { W2ab[i] = f2bf(W2a[i]); W2bb[i] = f2bf(W2b[i]); }
}

// ---------------- K1: x = relu(h @ W1^T + b1) -> bf16 ----------------
// R9 structure (128x256 tile, 4 waves of 64x128, acc[4][8], dbuf, 1 barrier/
// iter, gld16-B, reg-staged A) + two fixes:
//  (1) T2 XOR-swizzle on BOTH LDS tiles. Rows are 64B ([.][32 ushorts]),
//      frag reads are 16B at slot g with row varying per lane -> old layout
//      was a 4-8-way bank conflict. New: 16B-slot' = chunk ^ ((row>>1)&3)
//      -> bank = (row&1)<<4 | slot<<2 | dw, fully spread: 2-way (free) on
//      reads and on the A ds_writes. B keeps a LINEAR gld16 dst; its global
//      SOURCE is inverse-swizzled (G21 both-sides rule).
//  (2) bijective XCD remap (782 = 8*97+6) so the 2 col-tiles of each row-
//      tile run on the same XCD -> A panel served from that XCD's L2.
__global__ __launch_bounds__(256, 2) void gemm1(
    const float* __restrict__ h, const unsigned short* __restrict__ W1b,
    const float* __restrict__ b1, unsigned short* __restrict__ xb) {
  __shared__ __align__(16) unsigned short As[2][128 * 32];  // 2 x 8 KB
  __shared__ __align__(16) unsigned short Bs[2][256 * 32];  // 2 x 16 KB

  const int t  = threadIdx.x;
  const int l  = t & 63;
  const int w  = t >> 6;          // 0..3
  const int wr = w >> 1;          // 0..1 (row half: 64 rows)
  const int wc = w & 1;           // 0..1 (col half: 128 cols)
  const int g  = l >> 4;          // 0..3
  const int lr = l & 15;

  // bijective XCD remap (m204): i -> v so each XCD owns a contiguous v-range
  const int i   = blockIdx.x;
  const int xcd = i & 7;
  const int pos = i >> 3;
  const int v   = (xcd < 6 ? xcd * 98 : 6 * 98 + (xcd - 6) * 97) + pos;
  const int rt  = v >> 1;          // 0..390
  const int ct  = v & 1;           // 0..1
  const int rowBase = rt * 128;
  const int colBase = ct * 256;

  // ---- A staging: thread t covers rows t>>2 and 64+(t>>2), 32B chunk t&3 ----
  const int ar = t >> 2;
  const int aj = t & 3;
  int gr0 = rowBase + ar;       if (gr0 >= NPATCH) gr0 = NPATCH - 1;
  int gr1 = rowBase + 64 + ar;  if (gr1 >= NPATCH) gr1 = NPATCH - 1;
  const float* asrc0 = h + (size_t)gr0 * 1024 + aj * 8;
  const float* asrc1 = h + (size_t)gr1 * 1024 + aj * 8;
  // swizzled ds_write slot: aj ^ ((ar>>1)&3)   ((64+ar)>>1 == ar>>1 mod 4)
  const int aslot = aj ^ ((ar >> 1) & 3);
  const int adst0 = ar * 32 + aslot * 8;
  const int adst1 = (64 + ar) * 32 + aslot * 8;

  // ---- B staging: 4 rounds; round r covers col colBase+r*64+(t>>2) ----
  // linear LDS dst (r*2048 + t*8); source chunk inverse-swizzled so that
  // slot s=(t&3) holds chunk j = s ^ ((col>>1)&3) = (t&3) ^ ((t>>3)&3).
  const int bj = (t & 3) ^ ((t >> 3) & 3);
  const unsigned short* bsrc[4];
#pragma unroll
  for (int r = 0; r < 4; ++r)
    bsrc[r] = W1b + (size_t)(colBase + r * 64 + (t >> 2)) * 1024 + bj * 8;

  // ---- swizzled frag-read offsets: slot = g ^ ((lr>>1)&3) ----
  const int rslot = (g ^ ((lr >> 1) & 3)) * 8;

  f32x4 acc[4][8];
#pragma unroll
  for (int mm = 0; mm < 4; ++mm)
#pragma unroll
    for (int nn = 0; nn < 8; ++nn) acc[mm][nn] = (f32x4){0.f, 0.f, 0.f, 0.f};

  // ---- prologue: stage tile 0, preload A(1) regs ----
  float4 s00, s01, s10, s11;
  {
#pragma unroll
    for (int r = 0; r < 4; ++r) gld16(bsrc[r], &Bs[0][r * 2048 + t * 8]);
    float4 t00 = *(const float4*)(asrc0 + 0);
    float4 t01 = *(const float4*)(asrc0 + 4);
    float4 t10 = *(const float4*)(asrc1 + 0);
    float4 t11 = *(const float4*)(asrc1 + 4);
    *(bf16x8*)&As[0][adst0] = cvt8(t00, t01);
    *(bf16x8*)&As[0][adst1] = cvt8(t10, t11);
    s00 = *(const float4*)(asrc0 + 32);
    s01 = *(const float4*)(asrc0 + 36);
    s10 = *(const float4*)(asrc1 + 32);
    s11 = *(const float4*)(asrc1 + 36);
  }
  __syncthreads();

  int cur = 0;
  for (int kt = 0; kt < 32; ++kt) {
    // stage tile kt+1 into buf[cur^1] (free since the barrier ending kt-1)
    if (kt < 31) {
#pragma unroll
      for (int r = 0; r < 4; ++r)
        gld16(bsrc[r] + (kt + 1) * 32, &Bs[cur ^ 1][r * 2048 + t * 8]);
      *(bf16x8*)&As[cur ^ 1][adst0] = cvt8(s00, s01);
      *(bf16x8*)&As[cur ^ 1][adst1] = cvt8(s10, s11);
      if (kt < 30) {
        s00 = *(const float4*)(asrc0 + (kt + 2) * 32);
        s01 = *(const float4*)(asrc0 + (kt + 2) * 32 + 4);
        s10 = *(const float4*)(asrc1 + (kt + 2) * 32);
        s11 = *(const float4*)(asrc1 + (kt + 2) * 32 + 4);
      }
    }
    // compute tile kt from buf[cur] (swizzled reads)
    bf16x8 af[4], bfr[8];
#pragma unroll
    for (int mm = 0; mm < 4; ++mm)
      af[mm] = *(const bf16x8*)&As[cur][(wr * 64 + mm * 16 + lr) * 32 + rslot];
#pragma unroll
    for (int nn = 0; nn < 8; ++nn)
      bfr[nn] = *(const bf16x8*)&Bs[cur][(wc * 128 + nn * 16 + lr) * 32 + rslot];
#pragma unroll
    for (int mm = 0; mm < 4; ++mm)
#pragma unroll
      for (int nn = 0; nn < 8; ++nn)
        acc[mm][nn] = __builtin_amdgcn_mfma_f32_16x16x32_bf16(af[mm], bfr[nn], acc[mm][nn], 0, 0, 0);
    __syncthreads();
    cur ^= 1;
  }

  // epilogue: relu + bias, store bf16
  float b1v[8];
#pragma unroll
  for (int nn = 0; nn < 8; ++nn) b1v[nn] = b1[colBase + wc * 128 + nn * 16 + lr];
#pragma unroll
  for (int mm = 0; mm < 4; ++mm) {
    const int rb0 = rowBase + wr * 64 + mm * 16 + g * 4;
#pragma unroll
    for (int r = 0; r < 4; ++r) {
      const int row = rb0 + r;
      if (row < NPATCH) {
        unsigned short* xrow = xb + (size_t)row * 512 + colBase + wc * 128;
#pragma unroll
        for (int nn = 0; nn < 8; ++nn) {
          float vv = acc[mm][nn][r] + b1v[nn];
          vv = vv > 0.f ? vv : 0.f;
          xrow[nn * 16 + lr] = cvt_bf16(vv);
        }
      }
    }
  }
}

// ---------------- K2: fa=sig(x@W2a^T+b2a), fb=tanh(x@W2b^T+b2b),
//                      params=(fa*fb)@W3^T+b3, scatter mu/logvar ----------------
// 64 rows/block, full 256 cols; 4 waves, each 64 rows x 64 cols, dual acc.
__global__ __launch_bounds__(256, 2) void gemm2(
    const unsigned short* __restrict__ xb,
    const unsigned short* __restrict__ W2ab, const unsigned short* __restrict__ W2bb,
    const float* __restrict__ b2a, const float* __restrict__ b2b,
    const float* __restrict__ W3, const float* __restrict__ b3,
    const int* __restrict__ coords,
    float* __restrict__ mug, float* __restrict__ lvg) {
  __shared__ __align__(16) unsigned short xs[64 * 40];
  __shared__ __align__(16) unsigned short was[256 * 40];
  __shared__ __align__(16) unsigned short wbs[256 * 40];
  __shared__ float pmu_s[4][64];
  __shared__ float plv_s[4][64];

  const int t = threadIdx.x;
  const int l = t & 63;
  const int w = t >> 6;
  const int g = l >> 4, lr = l & 15;
  const int rowBase = blockIdx.x * 64;

  f32x4 aa[4][4], ab[4][4];
#pragma unroll
  for (int m = 0; m < 4; ++m)
#pragma unroll
    for (int n = 0; n < 4; ++n) {
      aa[m][n] = (f32x4){0.f, 0.f, 0.f, 0.f};
      ab[m][n] = (f32x4){0.f, 0.f, 0.f, 0.f};
    }

  const int xrow = t >> 2;           // 0..63
  const int xc0  = (t & 3) * 8;      // 0,8,16,24
  const int grow = rowBase + xrow;
  const bool xval = grow < NPATCH;

  for (int kt = 0; kt < 16; ++kt) {
    const int k0 = kt * 32;
    __syncthreads();
    if (xval) {
      *(int4*)&xs[xrow * 40 + xc0] = *(const int4*)(xb + (size_t)grow * 512 + k0 + xc0);
    } else {
      int4 z = {0, 0, 0, 0};
      *(int4*)&xs[xrow * 40 + xc0] = z;
    }
#pragma unroll
    for (int j = 0; j < 4; ++j) {
      int rrow = (t >> 2) + 64 * j;  // 0..255
      *(int4*)&was[rrow * 40 + xc0] = *(const int4*)(W2ab + (size_t)rrow * 512 + k0 + xc0);
      *(int4*)&wbs[rrow * 40 + xc0] = *(const int4*)(W2bb + (size_t)rrow * 512 + k0 + xc0);
    }
    __syncthreads();

    bf16x8 af[4], ba[4], bb[4];
#pragma unroll
    for (int m = 0; m < 4; ++m)
      af[m] = *(const bf16x8*)&xs[(m * 16 + lr) * 40 + g * 8];
#pragma unroll
    for (int n = 0; n < 4; ++n) {
      int brow = w * 64 + n * 16 + lr;
      ba[n] = *(const bf16x8*)&was[brow * 40 + g * 8];
      bb[n] = *(const bf16x8*)&wbs[brow * 40 + g * 8];
    }
#pragma unroll
    for (int m = 0; m < 4; ++m)
#pragma unroll
      for (int n = 0; n < 4; ++n) {
        aa[m][n] = __builtin_amdgcn_mfma_f32_16x16x32_bf16(af[m], ba[n], aa[m][n], 0, 0, 0);
        ab[m][n] = __builtin_amdgcn_mfma_f32_16x16x32_bf16(af[m], bb[n], ab[m][n], 0, 0, 0);
      }
  }

  // epilogue: per output row, mu/lv = sum_col (sig*tanh)*W3[.,col]
  float b2av[4], b2bv[4], w30v[4], w31v[4];
#pragma unroll
  for (int n = 0; n < 4; ++n) {
    int col = w * 64 + n * 16 + lr;
    b2av[n] = b2a[col]; b2bv[n] = b2b[col];
    w30v[n] = W3[col];  w31v[n] = W3[256 + col];
  }
#pragma unroll
  for (int m = 0; m < 4; ++m) {
#pragma unroll
    for (int r = 0; r < 4; ++r) {
      float pm = 0.f, pl = 0.f;
#pragma unroll
      for (int n = 0; n < 4; ++n) {
        float a = 1.f / (1.f + __expf(-(aa[m][n][r] + b2av[n])));
        float b = tanhf(ab[m][n][r] + b2bv[n]);
        float p = a * b;
        pm += p * w30v[n];
        pl += p * w31v[n];
      }
#pragma unroll
      for (int d = 1; d < 16; d <<= 1) {
        pm += __shfl_xor(pm, d, 64);
        pl += __shfl_xor(pl, d, 64);
      }
      if (lr == 0) {
        pmu_s[w][m * 16 + g * 4 + r] = pm;
        plv_s[w][m * 16 + g * 4 + r] = pl;
      }
    }
  }
  __syncthreads();
  if (t < 64) {
    float mu = pmu_s[0][t] + pmu_s[1][t] + pmu_s[2][t] + pmu_s[3][t] + b3[0];
    float lv = plv_s[0][t] + plv_s[1][t] + plv_s[2][t] + plv_s[3][t] + b3[1];
    int row = rowBase + t;
    if (row < NPATCH) {
      int gx = coords[2 * row] >> 8;       // /256
      int gy = coords[2 * row + 1] >> 8;
      int cell = gy * GC + gx;
      mug[cell] = mu;
      lvg[cell] = lv;
    }
  }
}

// ---------------- K3: kl_div, 3x3 conv, reparam, sigmoid -> A grid ----------------
__global__ void grid_ops(const float* __restrict__ mug, const float* __restrict__ lvg,
                         const float* __restrict__ eps, const float* __restrict__ kern,
                         const int* __restrict__ slide, float* __restrict__ Ag,
                         float* __restrict__ out_kl) {
  int cell = blockIdx.x * 256 + threadIdx.x;
  int iy = cell >> 8, ix = cell & 255;
  float mu = mug[cell], lv = lvg[cell];
  int sl = slide[0];
  float pm  = (sl == 0) ? -5.0f : 0.0f;
  float plv = (sl == 0) ? -1.0f : 3.0f;
  float d = pm - mu;
  out_kl[cell] = (plv - lv) * 0.5f + (lv * lv + d * d) / (2.0f * plv * plv) - 0.5f;
  float s = 0.f;
#pragma unroll
  for (int dy = 0; dy < 3; ++dy) {
#pragma unroll
    for (int dx = 0; dx < 3; ++dx) {
      int y = iy + dy - 1, x = ix + dx - 1;
      if (y >= 0 && y < GC && x >= 0 && x < GC)
        s += mug[y * GC + x] * kern[dy * 3 + dx];
    }
  }
  float sample = s + eps[cell] * __expf(0.5f * lv);
  Ag[cell] = 1.f / (1.f + __expf(-sample));
}

// ---------------- K4: gather patch_A, accumulate sumA and patch_A @ x ----------------
__global__ __launch_bounds__(256) void patch_pass(
    const float* __restrict__ Ag, const int* __restrict__ coords,
    const unsigned short* __restrict__ xb, float* __restrict__ out_pA,
    float* __restrict__ Mpart, float* __restrict__ sumA) {
  __shared__ float als[256];
  __shared__ float swave[4];
  const int t = threadIdx.x;
  const int base = blockIdx.x * 256;
  const int row = base + t;
  float a = 0.f;
  if (row < NPATCH) {
    int gx = coords[2 * row] >> 8;
    int gy = coords[2 * row + 1] >> 8;
    a = Ag[gy * GC + gx];
    out_pA[row] = a;
  }
  als[t] = a;
  float sa = a;
#pragma unroll
  for (int d = 1; d < 64; d <<= 1) sa += __shfl_xor(sa, d, 64);
  if ((t & 63) == 0) swave[t >> 6] = sa;
  __syncthreads();
  if (t == 0) atomicAdd(sumA, swave[0] + swave[1] + swave[2] + swave[3]);

  const int nrows = min(256, NPATCH - base);
  float m0 = 0.f, m1 = 0.f;
  for (int r = 0; r < nrows; ++r) {
    float av = als[r];
    const uint32_t* p = (const uint32_t*)(xb + (size_t)(base + r) * 512);
    uint32_t v = p[t];
    m0 += av * bf2f(v & 0xFFFFu);
    m1 += av * bf2f(v >> 16);
  }
  atomicAdd(&Mpart[t * 2 + 0], m0);
  atomicAdd(&Mpart[t * 2 + 1], m1);
}

// ---------------- K5: logits, softmax, argmax, small outputs ----------------
__global__ void finalize(const float* __restrict__ Mpart, const float* __restrict__ sumA,
                         const float* __restrict__ Wc, const float* __restrict__ bc,
                         float* __restrict__ out) {
  const int t = threadIdx.x;  // 64 threads
  float s = sumA[0];
  float l0 = 0.f, l1 = 0.f;
#pragma unroll
  for (int j = 0; j < 8; ++j) {
    int c = t * 8 + j;
    float m = Mpart[c] / s;
    l0 += m * Wc[c];
    l1 += m * Wc[512 + c];
  }
#pragma unroll
  for (int d = 1; d < 64; d <<= 1) {
    l0 += __shfl_xor(l0, d, 64);
    l1 += __shfl_xor(l1, d, 64);
  }
  if (t == 0) {
    l0 += bc[0]; l1 += bc[1];
    float mx = fmaxf(l0, l1);
    float e0 = __expf(l0 - mx), e1 = __expf(l1 - mx);
    float inv = 1.f / (e0 + e1);
    float p0 = e0 * inv, p1 = e1 * inv;
    out[0] = l0; out[1] = l1;            // top_instance
    out[2] = p0; out[3] = p1;            // Y_prob
    out[4] = (l1 > l0) ? 1.0f : 0.0f;    // Y_hat
    out[65541] = p0; out[65542] = p1;    // y_probs
  }
}

extern "C" void kernel_launch(void* const* d_in, const int* in_sizes, int n_in,
                              void* d_out, int out_size, void* d_ws, size_t ws_size,
                              hipStream_t stream) {
  const float* h      = (const float*)d_in[0];
  const int*   coords = (const int*)d_in[1];
  const float* eps    = (const float*)d_in[2];
  const float* W1     = (const float*)d_in[3];
  const float* b1     = (const float*)d_in[4];
  const float* W2a    = (const float*)d_in[5];
  const float* b2a    = (const float*)d_in[6];
  const float* W2b    = (const float*)d_in[7];
  const float* b2b    = (const float*)d_in[8];
  const float* W3     = (const float*)d_in[9];
  const float* b3     = (const float*)d_in[10];
  const float* Wc     = (const float*)d_in[11];
  const float* bc     = (const float*)d_in[12];
  const float* kern   = (const float*)d_in[13];
  const int*   slide  = (const int*)d_in[16];
  float* out = (float*)d_out;
  char*  ws  = (char*)d_ws;

  unsigned short* xb   = (unsigned short*)(ws + XB_OFF);
  unsigned short* W1b  = (unsigned short*)(ws + W1B_OFF);
  unsigned short* W2ab = (unsigned short*)(ws + W2AB_OFF);
  unsigned short* W2bb = (unsigned short*)(ws + W2BB_OFF);
  float* mug   = (float*)(ws + MUG_OFF);
  float* lvg   = (float*)(ws + LVG_OFF);
  float* Ag    = (float*)(ws + AG_OFF);
  float* Mpart = (float*)(ws + MPART_OFF);
  float* sumA  = (float*)(ws + SUMA_OFF);

  hipMemsetAsync(ws + MUG_OFF, 0, ZERO_BYTES, stream);

  convert_weights<<<2048, 256, 0, stream>>>(W1, W2a, W2b, W1b, W2ab, W2bb);
  gemm1<<<782, 256, 0, stream>>>(h, W1b, b1, xb);
  gemm2<<<782, 256, 0, stream>>>(xb, W2ab, W2bb, b2a, b2b, W3, b3, coords, mug, lvg);
  grid_ops<<<256, 256, 0, stream>>>(mug, lvg, eps, kern, slide, Ag, out + 5);
  patch_pass<<<196, 256, 0, stream>>>(Ag, coords, xb, out + 65543, Mpart, sumA);
  finalize<<<1, 64, 0, stream>>>(Mpart, sumA, Wc, bc, out);
}